// Round 8
// baseline (414.699 us; speedup 1.0000x reference)
//
#include <hip/hip_runtime.h>
#include <hip/hip_bf16.h>

typedef __bf16 bf16_t;
typedef __bf16 bf16x4 __attribute__((ext_vector_type(4)));
typedef __bf16 bf16x8 __attribute__((ext_vector_type(8)));
typedef float  f32x4  __attribute__((ext_vector_type(4)));

#define GLD_LDS16(gptr, lptr)                                                        \
    __builtin_amdgcn_global_load_lds((__attribute__((address_space(1))) void*)(gptr),\
                                     (__attribute__((address_space(3))) void*)(lptr),\
                                     16, 0, 0)

constexpr int Bc = 2, Tc = 2048, Ec = 2048, Hc = 16, Dc = 128;
constexpr int Mtok = Bc * Tc;  // 4096

__device__ __forceinline__ bf16x8 cvt8(const float* p) {
    f32x4 a = *(const f32x4*)p;
    f32x4 b = *(const f32x4*)(p + 4);
    bf16x8 r;
    r[0] = (bf16_t)a[0]; r[1] = (bf16_t)a[1];
    r[2] = (bf16_t)a[2]; r[3] = (bf16_t)a[3];
    r[4] = (bf16_t)b[0]; r[5] = (bf16_t)b[1];
    r[6] = (bf16_t)b[2]; r[7] = (bf16_t)b[3];
    return r;
}

// 16-lane butterfly max via DPP (VALU pipe).
__device__ __forceinline__ float fmax_dpp16(float x) {
    int xi;
    xi = __builtin_amdgcn_mov_dpp(__builtin_bit_cast(int, x), 0xB1, 0xF, 0xF, true);
    x = fmaxf(x, __builtin_bit_cast(float, xi));
    xi = __builtin_amdgcn_mov_dpp(__builtin_bit_cast(int, x), 0x4E, 0xF, 0xF, true);
    x = fmaxf(x, __builtin_bit_cast(float, xi));
    xi = __builtin_amdgcn_mov_dpp(__builtin_bit_cast(int, x), 0x141, 0xF, 0xF, true);
    x = fmaxf(x, __builtin_bit_cast(float, xi));
    xi = __builtin_amdgcn_mov_dpp(__builtin_bit_cast(int, x), 0x140, 0xF, 0xF, true);
    x = fmaxf(x, __builtin_bit_cast(float, xi));
    return x;
}

__global__ void convert_bf16(const float* __restrict__ src, bf16_t* __restrict__ dst) {
    size_t i = ((size_t)blockIdx.x * 256 + threadIdx.x) * 8;
    *(bf16x8*)&dst[i] = cvt8(src + i);
}

// Convert Wq,Wk,Wv,Wo (fp32 [E][E]) to one contiguous bf16 buffer w4[4][E][E].
__global__ void convert_w(const float* __restrict__ Wq, const float* __restrict__ Wk,
                          const float* __restrict__ Wv, const float* __restrict__ Wo,
                          bf16_t* __restrict__ w4) {
    int blk = blockIdx.x;          // 0..8191, 2048 blocks per matrix
    int wi  = blk >> 11;           // 0..3
    const float* src = (wi == 0) ? Wq : (wi == 1) ? Wk : (wi == 2) ? Wv : Wo;
    bf16_t* dst = w4 + (size_t)wi * Ec * Ec;
    size_t i = ((size_t)(blk & 2047) * 256 + threadIdx.x) * 8;
    *(bf16x8*)&dst[i] = cvt8(src + i);
}

// ===========================================================================
// Zero-tail fused QKV GEMM (verified R4: 102 us, 43% MfmaUtil).
// ===========================================================================
__global__ __launch_bounds__(512, 2) void gemm_qkv_z(const bf16_t* __restrict__ A,
                                                     const bf16_t* __restrict__ w3,
                                                     const float* __restrict__ bq,
                                                     const float* __restrict__ bk,
                                                     const float* __restrict__ bv,
                                                     bf16_t* __restrict__ qo,
                                                     bf16_t* __restrict__ ko,
                                                     bf16_t* __restrict__ vto) {
    __shared__ __align__(16) bf16_t ldsA[3 * 8192];    // [buf][256][32]  48KB
    __shared__ __align__(16) bf16_t ldsB[3 * 12288];   // [buf][384][32]  72KB

    const int tid  = threadIdx.x;
    const int wave = tid >> 6;
    const int lane = tid & 63;
    const int g    = lane >> 4;
    const int n16  = lane & 15;
    const int wm   = wave >> 2;          // 0..1  (M half: 128 rows)
    const int wn   = wave & 3;           // 0..3  (N quarter: 96 cols)
    const int m0   = blockIdx.x * 256;
    const int n0   = blockIdx.y * 384;   // global col in fused N=6144
    const int K    = Ec;

    const int sr   = tid >> 2;                                  // 0..127
    const int scol = (((tid & 3) ^ ((tid >> 3) & 3)) << 3);     // elems
    const bf16_t* srcA = A  + (size_t)(m0 + sr) * K + scol;
    const bf16_t* srcB = w3 + (size_t)(n0 + sr) * K + scol;
    const int dwave = wave * 512;   // wave-uniform dest base (elems)

    const int fsw = (n16 >> 1) & 3;      // read-side swizzle

    constexpr int NT = Ec / 32;  // 64 K-tiles

#define STG_A2(jj, buf)                                                         \
    do { if ((jj) < NT) {                                                       \
        const bf16_t* _s = srcA + (jj) * 32;                                    \
        bf16_t* _d = &ldsA[(buf) * 8192 + dwave];                               \
        GLD_LDS16(_s, _d);                                                      \
        GLD_LDS16(_s + (size_t)128 * K, _d + 4096);                             \
    } } while (0)
#define STG_B1(jj, buf)                                                         \
    do { if ((jj) < NT) {                                                       \
        GLD_LDS16(srcB + (jj) * 32, &ldsB[(buf) * 12288 + dwave]);              \
    } } while (0)
#define STG_B2(jj, buf)                                                         \
    do { if ((jj) < NT) {                                                       \
        const bf16_t* _s = srcB + (jj) * 32;                                    \
        bf16_t* _d = &ldsB[(buf) * 12288 + dwave];                              \
        GLD_LDS16(_s + (size_t)128 * K, _d + 4096);                             \
        GLD_LDS16(_s + (size_t)256 * K, _d + 8192);                             \
    } } while (0)

    f32x4 acc[8][6] = {};
    bf16x8 af[4], af2[4], bfr[6];

    STG_A2(0, 0); STG_B1(0, 0); STG_B2(0, 0);
    STG_A2(1, 1); STG_B1(1, 1); STG_B2(1, 1);
    asm volatile("s_waitcnt vmcnt(5)" ::: "memory");   // tile 0 resident
    __builtin_amdgcn_s_barrier();
    asm volatile("" ::: "memory");

    int bc = 0;  // current buffer
    int bi = 2;  // issue buffer (tile j+2)
#pragma unroll 1
    for (int j = 0; j < NT; ++j) {
        const bf16_t* la = &ldsA[bc * 8192];
        const bf16_t* lb = &ldsB[bc * 12288];

#pragma unroll
        for (int mt = 0; mt < 4; ++mt)
            af[mt] = *(const bf16x8*)&la[(wm * 128 + mt * 16 + n16) * 32 +
                                         ((g ^ fsw) << 3)];
#pragma unroll
        for (int l = 0; l < 6; ++l)
            bfr[l] = *(const bf16x8*)&lb[(wn * 96 + l * 16 + n16) * 32 +
                                         ((g ^ fsw) << 3)];
        STG_A2(j + 2, bi);
        STG_B1(j + 2, bi);
        asm volatile("s_waitcnt lgkmcnt(0)" ::: "memory");
        __builtin_amdgcn_sched_barrier(0);
        __builtin_amdgcn_s_setprio(1);
#pragma unroll
        for (int mt = 0; mt < 4; ++mt)
#pragma unroll
            for (int l = 0; l < 6; ++l)
                acc[mt][l] = __builtin_amdgcn_mfma_f32_16x16x32_bf16(
                    af[mt], bfr[l], acc[mt][l], 0, 0, 0);
        __builtin_amdgcn_s_setprio(0);
        __builtin_amdgcn_s_barrier();
        asm volatile("" ::: "memory");

#pragma unroll
        for (int mt = 0; mt < 4; ++mt)
            af2[mt] = *(const bf16x8*)&la[(wm * 128 + 64 + mt * 16 + n16) * 32 +
                                          ((g ^ fsw) << 3)];
        STG_B2(j + 2, bi);
        asm volatile("s_waitcnt lgkmcnt(0)" ::: "memory");
        __builtin_amdgcn_sched_barrier(0);
        __builtin_amdgcn_s_setprio(1);
#pragma unroll
        for (int mt = 0; mt < 4; ++mt)
#pragma unroll
            for (int l = 0; l < 6; ++l)
                acc[4 + mt][l] = __builtin_amdgcn_mfma_f32_16x16x32_bf16(
                    af2[mt], bfr[l], acc[4 + mt][l], 0, 0, 0);
        __builtin_amdgcn_s_setprio(0);

        if (j < NT - 2)      { asm volatile("s_waitcnt vmcnt(5)" ::: "memory"); }
        else if (j < NT - 1) { asm volatile("s_waitcnt vmcnt(0)" ::: "memory"); }
        __builtin_amdgcn_s_barrier();
        asm volatile("" ::: "memory");

        bc = (bc == 2) ? 0 : bc + 1;
        bi = (bi == 2) ? 0 : bi + 1;
    }
#undef STG_A2
#undef STG_B1
#undef STG_B2

#pragma unroll
    for (int l = 0; l < 6; ++l) {
        int n   = n0 + wn * 96 + l * 16 + n16;
        int mat = n >> 11;            // 0=Q 1=K 2=V
        int nn  = n & 2047;
        const float* bp = (mat == 0) ? bq : (mat == 1) ? bk : bv;
        float bn = bp[nn];
        int h = nn >> 7, d = nn & (Dc - 1);
#pragma unroll
        for (int i = 0; i < 8; ++i) {
            int mb = m0 + wm * 128 + (i >> 2) * 64 + (i & 3) * 16 + g * 4;
            int b = mb >> 11, t = mb & (Tc - 1);
            if (mat == 2) {
                bf16x4 pk;
#pragma unroll
                for (int r = 0; r < 4; ++r) pk[r] = (bf16_t)(acc[i][l][r] + bn);
                *(bf16x4*)&vto[(((size_t)(b * Hc + h)) * Dc + d) * Tc + t] = pk;
            } else {
                bf16_t* outb = (mat == 0) ? qo : ko;
#pragma unroll
                for (int r = 0; r < 4; ++r)
                    outb[(((size_t)(b * Hc + h)) * Tc + (t + r)) * Dc + d] =
                        (bf16_t)(acc[i][l][r] + bn);
            }
        }
    }
}

// ===========================================================================
// Pipelined output-projection GEMM (verified R1).
// ===========================================================================
__global__ __launch_bounds__(512, 2) void gemm_out_p(const bf16_t* __restrict__ A,
                                                     const bf16_t* __restrict__ W,
                                                     const float* __restrict__ bias,
                                                     float* __restrict__ out) {
    __shared__ __align__(16) bf16_t ldsA[3 * 256 * 32];
    __shared__ __align__(16) bf16_t ldsB[3 * 128 * 32];

    const int tid  = threadIdx.x;
    const int wave = tid >> 6;
    const int lane = tid & 63;
    const int g    = lane >> 4;
    const int n16  = lane & 15;
    const int wm   = wave >> 1;
    const int wn   = wave & 1;
    const int m0   = blockIdx.x * 256;
    const int n0   = blockIdx.y * 128;
    const int K    = Ec;

    const int sr   = tid >> 2;
    const int scol = (((tid & 3) ^ ((tid >> 3) & 3)) << 3);
    const bf16_t* gA0 = A + (size_t)(m0 + sr) * K + scol;
    const bf16_t* gA1 = A + (size_t)(m0 + 128 + sr) * K + scol;
    const bf16_t* gB  = W + (size_t)(n0 + sr) * K + scol;
    const int dL = wave * 512;

    const int fsw = (n16 >> 1) & 3;
    const int rAo = (wm * 64 + n16) * 32 + ((g ^ fsw) << 3);
    const int rBo = (wn * 64 + n16) * 32 + ((g ^ fsw) << 3);

    f32x4 acc[4][4] = {};

    constexpr int NT = Ec / 32;
#pragma unroll
    for (int tt = 0; tt < 2; ++tt) {
        GLD_LDS16(gA0 + tt * 32, &ldsA[tt * 8192 + dL]);
        GLD_LDS16(gA1 + tt * 32, &ldsA[tt * 8192 + 4096 + dL]);
        GLD_LDS16(gB  + tt * 32, &ldsB[tt * 4096 + dL]);
    }

    int bc = 0, bi = 2;
#pragma unroll 1
    for (int t = 0; t < NT; ++t) {
        if (t < NT - 1) { asm volatile("s_waitcnt vmcnt(3)" ::: "memory"); }
        else            { asm volatile("s_waitcnt vmcnt(0)" ::: "memory"); }
        __builtin_amdgcn_s_barrier();
        asm volatile("" ::: "memory");

        const bf16_t* la = &ldsA[bc * 8192];
        const bf16_t* lb = &ldsB[bc * 4096];
        bf16x8 af[4], bfr[4];
#pragma unroll
        for (int mt = 0; mt < 4; ++mt) af[mt] = *(const bf16x8*)&la[rAo + mt * 512];
#pragma unroll
        for (int nt = 0; nt < 4; ++nt) bfr[nt] = *(const bf16x8*)&lb[rBo + nt * 512];

        if (t + 2 < NT) {
            GLD_LDS16(gA0 + (t + 2) * 32, &ldsA[bi * 8192 + dL]);
            GLD_LDS16(gA1 + (t + 2) * 32, &ldsA[bi * 8192 + 4096 + dL]);
            GLD_LDS16(gB  + (t + 2) * 32, &ldsB[bi * 4096 + dL]);
        }

        asm volatile("s_waitcnt lgkmcnt(0)" ::: "memory");
        __builtin_amdgcn_sched_barrier(0);
        __builtin_amdgcn_s_setprio(1);
#pragma unroll
        for (int mt = 0; mt < 4; ++mt)
#pragma unroll
            for (int nt = 0; nt < 4; ++nt)
                acc[mt][nt] = __builtin_amdgcn_mfma_f32_16x16x32_bf16(
                    af[mt], bfr[nt], acc[mt][nt], 0, 0, 0);
        __builtin_amdgcn_s_setprio(0);

        bc = (bc == 2) ? 0 : bc + 1;
        bi = (bi == 2) ? 0 : bi + 1;
    }

    const int row_off = wm * 64;
    const int col_off = wn * 64;
#pragma unroll
    for (int nt = 0; nt < 4; ++nt) {
        int n = n0 + col_off + nt * 16 + n16;
        float bn = bias[n];
#pragma unroll
        for (int mt = 0; mt < 4; ++mt) {
            int mb = m0 + row_off + mt * 16 + g * 4;
#pragma unroll
            for (int r = 0; r < 4; ++r)
                out[(size_t)(mb + r) * Ec + n] = acc[mt][nt][r] + bn;
        }
    }
}

// ---------------------------------------------------------------------------
// Fallback variants (fp32 weights, register-staged) — small-workspace path.
// ---------------------------------------------------------------------------
__global__ __launch_bounds__(256) void gemm_qkv(const bf16_t* __restrict__ A,
                                                const float* __restrict__ Wq,
                                                const float* __restrict__ Wk,
                                                const float* __restrict__ Wv,
                                                const float* __restrict__ bq,
                                                const float* __restrict__ bk,
                                                const float* __restrict__ bv,
                                                bf16_t* __restrict__ qo,
                                                bf16_t* __restrict__ ko,
                                                bf16_t* __restrict__ vto) {
    __shared__ __align__(16) bf16_t ldsA[128 * 32];
    __shared__ __align__(16) bf16_t ldsB[128 * 32];

    const int tid  = threadIdx.x;
    const int wave = tid >> 6;
    const int lane = tid & 63;
    const int g    = lane >> 4;
    const int n16  = lane & 15;
    const int m0   = blockIdx.x * 128;
    const int mat  = blockIdx.y >> 4;
    const int n0   = (blockIdx.y & 15) * 128;
    const int row_off = (wave >> 1) * 64;
    const int col_off = (wave & 1) * 64;
    const int K = Ec;

    const float* W    = (mat == 0) ? Wq : (mat == 1) ? Wk : Wv;
    const float* bias = (mat == 0) ? bq : (mat == 1) ? bk : bv;

    f32x4 acc[4][4] = {};

    const int r0 = tid >> 2;
    const int cc = tid & 3;
    const size_t a0 = (size_t)(m0 + r0) * K + cc * 8;
    const size_t a1 = (size_t)(m0 + r0 + 64) * K + cc * 8;
    const float* pb0 = W + (size_t)(n0 + r0) * K + cc * 8;
    const float* pb1 = W + (size_t)(n0 + r0 + 64) * K + cc * 8;

    for (int k0 = 0; k0 < K; k0 += 32) {
        bf16x8 vb0 = cvt8(pb0 + k0);
        bf16x8 vb1 = cvt8(pb1 + k0);
        __syncthreads();
        GLD_LDS16(A + a0 + k0, &ldsA[(wave * 64) * 8]);
        GLD_LDS16(A + a1 + k0, &ldsA[(256 + wave * 64) * 8]);
        *(bf16x8*)&ldsB[(size_t)tid * 8]         = vb0;
        *(bf16x8*)&ldsB[(size_t)(256 + tid) * 8] = vb1;
        __syncthreads();

        bf16x8 af[4], bfr[4];
#pragma unroll
        for (int mt = 0; mt < 4; ++mt)
            af[mt] = *(const bf16x8*)&ldsA[(row_off + mt * 16 + n16) * 32 + g * 8];
#pragma unroll
        for (int nt = 0; nt < 4; ++nt)
            bfr[nt] = *(const bf16x8*)&ldsB[(col_off + nt * 16 + n16) * 32 + g * 8];
#pragma unroll
        for (int mt = 0; mt < 4; ++mt)
#pragma unroll
            for (int nt = 0; nt < 4; ++nt)
                acc[mt][nt] = __builtin_amdgcn_mfma_f32_16x16x32_bf16(
                    af[mt], bfr[nt], acc[mt][nt], 0, 0, 0);
    }

#pragma unroll
    for (int nt = 0; nt < 4; ++nt) {
        int n = n0 + col_off + nt * 16 + n16;
        float bn = bias[n];
        int h = n >> 7, d = n & (Dc - 1);
#pragma unroll
        for (int mt = 0; mt < 4; ++mt) {
            int mb = m0 + row_off + mt * 16 + g * 4;
            int b = mb >> 11, t = mb & (Tc - 1);
            if (mat == 2) {
                bf16x4 pk;
#pragma unroll
                for (int r = 0; r < 4; ++r) pk[r] = (bf16_t)(acc[mt][nt][r] + bn);
                *(bf16x4*)&vto[(((size_t)(b * Hc + h)) * Dc + d) * Tc + t] = pk;
            } else {
                bf16_t* outb = (mat == 0) ? qo : ko;
#pragma unroll
                for (int r = 0; r < 4; ++r)
                    outb[(((size_t)(b * Hc + h)) * Tc + (t + r)) * Dc + d] =
                        (bf16_t)(acc[mt][nt][r] + bn);
            }
        }
    }
}

__global__ __launch_bounds__(256) void gemm_out(const bf16_t* __restrict__ A,
                                                const float* __restrict__ W,
                                                const float* __restrict__ bias,
                                                float* __restrict__ out,
                                                int M, int N, int K) {
    __shared__ __align__(16) bf16_t ldsA[128 * 32];
    __shared__ __align__(16) bf16_t ldsB[128 * 32];

    const int tid  = threadIdx.x;
    const int wave = tid >> 6;
    const int lane = tid & 63;
    const int g    = lane >> 4;
    const int n16  = lane & 15;
    const int m0 = blockIdx.x * 128;
    const int n0 = blockIdx.y * 128;
    const int row_off = (wave >> 1) * 64;
    const int col_off = (wave & 1) * 64;

    f32x4 acc[4][4] = {};

    const int r0 = tid >> 2;
    const int cc = tid & 3;
    const size_t a0 = (size_t)(m0 + r0) * K + cc * 8;
    const size_t a1 = (size_t)(m0 + r0 + 64) * K + cc * 8;
    const float* pb0 = W + (size_t)(n0 + r0) * K + cc * 8;
    const float* pb1 = W + (size_t)(n0 + r0 + 64) * K + cc * 8;

    for (int k0 = 0; k0 < K; k0 += 32) {
        bf16x8 vb0 = cvt8(pb0 + k0);
        bf16x8 vb1 = cvt8(pb1 + k0);
        __syncthreads();
        GLD_LDS16(A + a0 + k0, &ldsA[(wave * 64) * 8]);
        GLD_LDS16(A + a1 + k0, &ldsA[(256 + wave * 64) * 8]);
        *(bf16x8*)&ldsB[(size_t)tid * 8]         = vb0;
        *(bf16x8*)&ldsB[(size_t)(256 + tid) * 8] = vb1;
        __syncthreads();

        bf16x8 af[4], bfr[4];
#pragma unroll
        for (int mt = 0; mt < 4; ++mt)
            af[mt] = *(const bf16x8*)&ldsA[(row_off + mt * 16 + n16) * 32 + g * 8];
#pragma unroll
        for (int nt = 0; nt < 4; ++nt)
            bfr[nt] = *(const bf16x8*)&ldsB[(col_off + nt * 16 + n16) * 32 + g * 8];
#pragma unroll
        for (int mt = 0; mt < 4; ++mt)
#pragma unroll
            for (int nt = 0; nt < 4; ++nt)
                acc[mt][nt] = __builtin_amdgcn_mfma_f32_16x16x32_bf16(
                    af[mt], bfr[nt], acc[mt][nt], 0, 0, 0);
    }

#pragma unroll
    for (int nt = 0; nt < 4; ++nt) {
        int n = n0 + col_off + nt * 16 + n16;
        float bn = bias[n];
#pragma unroll
        for (int mt = 0; mt < 4; ++mt) {
            int mb = m0 + row_off + mt * 16 + g * 4;
#pragma unroll
            for (int r = 0; r < 4; ++r)
                out[(size_t)(mb + r) * N + n] = acc[mt][nt][r] + bn;
        }
    }
}

// ---------------------------------------------------------------------------
// RoPE in-place on q,k [B,H,T,D]; positions 1-indexed (t+1).
// ---------------------------------------------------------------------------
__global__ void rope_kernel(bf16_t* __restrict__ q, bf16_t* __restrict__ k) {
    int row = blockIdx.x * 4 + (threadIdx.x >> 6);  // (b*H+h)*T + t
    int d   = threadIdx.x & 63;
    int t   = row & (Tc - 1);
    float theta = powf(10000.0f, -(float)d * (1.0f / 64.0f));
    float ang   = (float)(t + 1) * theta;
    float sv, cv;
    sincosf(ang, &sv, &cv);
    size_t base = (size_t)row * Dc;
    float q1 = (float)q[base + d], q2 = (float)q[base + d + 64];
    q[base + d]      = (bf16_t)(q1 * cv - q2 * sv);
    q[base + d + 64] = (bf16_t)(q2 * cv + q1 * sv);
    float k1 = (float)k[base + d], k2 = (float)k[base + d + 64];
    k[base + d]      = (bf16_t)(k1 * cv - k2 * sv);
    k[base + d + 64] = (bf16_t)(k2 * cv + k1 * sv);
}

// ---------------------------------------------------------------------------
// Causal flash attention, QBLK=128 (2 m-frags/wave -> each K/V LDS fragment
// read feeds TWO MFMAs, halving LDS traffic per FLOP vs QBLK=64).
// q,k: [B,H,T,D] bf16; vt: [B,H,D,T] bf16; att out: [B,T,E] bf16.
// Grid (16, B*H): block x handles q-tile qt = 15-x (128 rows; long blocks
// dispatch first); nkt = 2*qt+2 K-tiles of 64. Wave w owns rows
// q0+w*32..+32 as m-frags mf in {0,1}. Padded LDS pitches (R4-proven),
// DPP max, classic online softmax, reg-prefetch staging.
// ---------------------------------------------------------------------------
constexpr int KP = 128 + 8;  // k_lds row pitch
constexpr int VP = 64 + 8;   // v_lds row pitch
constexpr int PP = 64 + 8;   // p_lds row pitch

__global__ __launch_bounds__(256, 2) void attn_kernel(const bf16_t* __restrict__ q,
                                                      const bf16_t* __restrict__ kmat,
                                                      const bf16_t* __restrict__ vt,
                                                      bf16_t* __restrict__ out) {
    __shared__ __align__(16) bf16_t k_lds[64 * KP];       // 17 KB
    __shared__ __align__(16) bf16_t v_lds[128 * VP];      // 18 KB
    __shared__ __align__(16) bf16_t p_lds[4 * 32 * PP];   // 18 KB

    const int tid  = threadIdx.x;
    const int wave = tid >> 6, lane = tid & 63;
    const int g = lane >> 4, n16 = lane & 15;
    const int qt = 15 - blockIdx.x;            // long blocks first
    const int bh = blockIdx.y;
    const int q0 = qt * 128;
    const int nkt = 2 * qt + 2;                // K-tiles of 64
    const size_t base = (size_t)bh * Tc * Dc;
    const int b = bh >> 4, h = bh & 15;
    const float sc2 = 0.08838834764831845f * 1.4426950408889634f;  // /sqrt(D)*log2e
    bf16_t* pw = &p_lds[wave * 32 * PP];

    const int kr_key = tid >> 4, kr_c = tid & 15;   // K staging: row i*16+kr_key
    const int vr_dd  = tid >> 3, vr_c = tid & 7;    // V staging: row i*32+vr_dd

    // Q fragments: rows q0 + wave*32 + mf*16 + n16
    bf16x8 qf[2][4];
#pragma unroll
    for (int mf = 0; mf < 2; ++mf) {
        const bf16_t* qp = q + base +
            (size_t)(q0 + wave * 32 + mf * 16 + n16) * Dc + g * 8;
#pragma unroll
        for (int kk = 0; kk < 4; ++kk) qf[mf][kk] = *(const bf16x8*)(qp + kk * 32);
    }

    float m_run[2][4], l_run[2][4];
#pragma unroll
    for (int mf = 0; mf < 2; ++mf)
#pragma unroll
        for (int r = 0; r < 4; ++r) { m_run[mf][r] = -1e30f; l_run[mf][r] = 0.0f; }
    f32x4 o_acc[2][8] = {};

    // preload tile 0 into registers
    bf16x8 rk[4], rv[4];
#pragma unroll
    for (int i = 0; i < 4; ++i)
        rk[i] = *(const bf16x8*)&kmat[base + (size_t)(i * 16 + kr_key) * Dc + kr_c * 8];
#pragma unroll
    for (int i = 0; i < 4; ++i)
        rv[i] = *(const bf16x8*)&vt[base + (size_t)(i * 32 + vr_dd) * Tc + vr_c * 8];

#pragma unroll 1
    for (int kt = 0; kt < nkt; ++kt) {
        const int k0 = kt * 64;
        __syncthreads();  // prior tile's LDS readers done
#pragma unroll
        for (int i = 0; i < 4; ++i)
            *(bf16x8*)&k_lds[(i * 16 + kr_key) * KP + kr_c * 8] = rk[i];
#pragma unroll
        for (int i = 0; i < 4; ++i)
            *(bf16x8*)&v_lds[(i * 32 + vr_dd) * VP + vr_c * 8] = rv[i];
        __syncthreads();  // staging visible

        if (kt + 1 < nkt) {  // prefetch next tile
            const int kn = k0 + 64;
#pragma unroll
            for (int i = 0; i < 4; ++i)
                rk[i] = *(const bf16x8*)&kmat[base + (size_t)(kn + i * 16 + kr_key) * Dc + kr_c * 8];
#pragma unroll
            for (int i = 0; i < 4; ++i)
                rv[i] = *(const bf16x8*)&vt[base + (size_t)(i * 32 + vr_dd) * Tc + kn + vr_c * 8];
        }

        // S = Q K^T: each kf read feeds BOTH m-frags
        f32x4 s0[4], s1[4];
#pragma unroll
        for (int nt = 0; nt < 4; ++nt) {
            f32x4 a0 = {}, a1 = {};
            int key = nt * 16 + n16;
#pragma unroll
            for (int kk = 0; kk < 4; ++kk) {
                bf16x8 kf = *(const bf16x8*)&k_lds[key * KP + kk * 32 + g * 8];
                a0 = __builtin_amdgcn_mfma_f32_16x16x32_bf16(qf[0][kk], kf, a0, 0, 0, 0);
                a1 = __builtin_amdgcn_mfma_f32_16x16x32_bf16(qf[1][kk], kf, a1, 0, 0, 0);
            }
            s0[nt] = a0; s1[nt] = a1;
        }

        const bool need_mask = (kt >= nkt - 2);  // diagonal band
#pragma unroll
        for (int mf = 0; mf < 2; ++mf) {
            f32x4* s_acc = mf ? s1 : s0;
            if (need_mask) {
#pragma unroll
                for (int nt = 0; nt < 4; ++nt) {
                    int key = k0 + nt * 16 + n16;
#pragma unroll
                    for (int r = 0; r < 4; ++r) {
                        int qq = q0 + wave * 32 + mf * 16 + g * 4 + r;
                        float v = s_acc[nt][r] * sc2;
                        s_acc[nt][r] = (key <= qq) ? v : -1e30f;
                    }
                }
            } else {
#pragma unroll
                for (int nt = 0; nt < 4; ++nt)
#pragma unroll
                    for (int r = 0; r < 4; ++r) s_acc[nt][r] *= sc2;
            }

            // online softmax (exp2 domain), DPP butterfly max
            float alpha[4];
#pragma unroll
            for (int r = 0; r < 4; ++r) {
                float rm = fmaxf(fmaxf(s_acc[0][r], s_acc[1][r]),
                                 fmaxf(s_acc[2][r], s_acc[3][r]));
                rm = fmax_dpp16(rm);
                float m_new = fmaxf(m_run[mf][r], rm);
                alpha[r] = __builtin_amdgcn_exp2f(m_run[mf][r] - m_new);
                m_run[mf][r] = m_new;
                float sum = 0.0f;
#pragma unroll
                for (int nt = 0; nt < 4; ++nt) {
                    float p = __builtin_amdgcn_exp2f(s_acc[nt][r] - m_new);
                    s_acc[nt][r] = p;
                    sum += p;
                }
                l_run[mf][r] = l_run[mf][r] * alpha[r] + sum;
            }
#pragma unroll
            for (int dt = 0; dt < 8; ++dt)
#pragma unroll
                for (int r = 0; r < 4; ++r) o_acc[mf][dt][r] *= alpha[r];

            // P (C/D) -> wave-private LDS rows mf*16 + g*4+r
#pragma unroll
            for (int nt = 0; nt < 4; ++nt) {
                int key = nt * 16 + n16;
#pragma unroll
                for (int r = 0; r < 4; ++r)
                    pw[(mf * 16 + g * 4 + r) * PP + key] = (bf16_t)s_acc[nt][r];
            }
        }

        bf16x8 pf[2][2];
#pragma unroll
        for (int mf = 0; mf < 2; ++mf)
#pragma unroll
            for (int kk = 0; kk < 2; ++kk)
                pf[mf][kk] = *(const bf16x8*)&pw[(mf * 16 + n16) * PP + kk * 32 + g * 8];

        // O += P V: each vf read feeds BOTH m-frags
#pragma unroll
        for (int dt = 0; dt < 8; ++dt) {
            int dd = dt * 16 + n16;
#pragma unroll
            for (int kk = 0; kk < 2; ++kk) {
                bf16x8 vf = *(const bf16x8*)&v_lds[dd * VP + kk * 32 + g * 8];
                o_acc[0][dt] = __builtin_amdgcn_mfma_f32_16x16x32_bf16(
                    pf[0][kk], vf, o_acc[0][dt], 0, 0, 0);
                o_acc[1][dt] = __builtin_amdgcn_mfma_f32_16x16x32_bf16(
                    pf[1][kk], vf, o_acc[1][dt], 0, 0, 0);
            }
        }
    }

    // epilogue: reduce per-lane l partials across the 16-lane row, write out
#pragma unroll
    for (int mf = 0; mf < 2; ++mf) {
        float inv_l[4];
#pragma unroll
        for (int r = 0; r < 4; ++r) {
            float s = l_run[mf][r];
            s += __shfl_xor(s, 1, 16);
            s += __shfl_xor(s, 2, 16);
            s += __shfl_xor(s, 4, 16);
            s += __shfl_xor(s, 8, 16);
            inv_l[r] = 1.0f / s;
        }
#pragma unroll
        for (int dt = 0; dt < 8; ++dt) {
            int d = dt * 16 + n16;
#pragma unroll
            for (int r = 0; r < 4; ++r) {
                int qq = q0 + wave * 32 + mf * 16 + g * 4 + r;
                out[((size_t)(b * Tc + qq)) * Ec + h * Dc + d] =
                    (bf16_t)(o_acc[mf][dt][r] * inv_l[r]);
            }
        }
    }
}

// ---------------------------------------------------------------------------
extern "C" void kernel_launch(void* const* d_in, const int* in_sizes, int n_in,
                              void* d_out, int out_size, void* d_ws, size_t ws_size,
                              hipStream_t stream) {
    const float* x  = (const float*)d_in[0];
    const float* Wq = (const float*)d_in[1];
    const float* bq = (const float*)d_in[2];
    const float* Wk = (const float*)d_in[3];
    const float* bk = (const float*)d_in[4];
    const float* Wv = (const float*)d_in[5];
    const float* bv = (const float*)d_in[6];
    const float* Wo = (const float*)d_in[7];
    const float* bo = (const float*)d_in[8];
    float* out = (float*)d_out;

    char* ws = (char*)d_ws;
    const size_t sz  = (size_t)Bc * Hc * Tc * Dc * sizeof(bf16_t);  // 16.78 MB
    const size_t szW = (size_t)Ec * Ec * sizeof(bf16_t);            // 8.39 MB
    bf16_t* q   = (bf16_t*)(ws);            // R0
    bf16_t* k   = (bf16_t*)(ws + sz);       // R1
    bf16_t* vt  = (bf16_t*)(ws + 2 * sz);   // R2 (written transposed)
    bf16_t* xb  = (bf16_t*)(ws + 3 * sz);   // R3: xb, then att
    bf16_t* att = xb;

    if (ws_size >= 4 * sz + 4 * szW) {
        // bf16 weights + zero-tail fused QKV GEMM + pipelined out GEMM
        bf16_t* w4 = (bf16_t*)(ws + 4 * sz);       // [4][E][E]: Wq,Wk,Wv,Wo
        convert_bf16<<<Mtok * Ec / (256 * 8), 256, 0, stream>>>(x, xb);
        convert_w<<<8192, 256, 0, stream>>>(Wq, Wk, Wv, Wo, w4);
        gemm_qkv_z<<<dim3(Mtok / 256, 16), 512, 0, stream>>>(xb, w4, bq, bk, bv,
                                                             q, k, vt);
        rope_kernel<<<Bc * Hc * Tc / 4, 256, 0, stream>>>(q, k);
        attn_kernel<<<dim3(16, Bc * Hc), 256, 0, stream>>>(q, k, vt, att);
        gemm_out_p<<<dim3(Mtok / 256, Ec / 128), 512, 0, stream>>>(
            att, w4 + 3 * (size_t)Ec * Ec, bo, out);
    } else {
        // fallback: fp32 weights, register-staged (proven path)
        convert_bf16<<<Mtok * Ec / (256 * 8), 256, 0, stream>>>(x, xb);
        gemm_qkv<<<dim3(Mtok / 128, 48), 256, 0, stream>>>(xb, Wq, Wk, Wv,
                                                           bq, bk, bv, q, k, vt);
        rope_kernel<<<Bc * Hc * Tc / 4, 256, 0, stream>>>(q, k);
        attn_kernel<<<dim3(16, Bc * Hc), 256, 0, stream>>>(q, k, vt, att);
        gemm_out<<<dim3(Mtok / 128, Ec / 128), 256, 0, stream>>>(att, Wo, bo, out,
                                                                 Mtok, Ec, Ec);
    }
}

// Round 9
// 380.756 us; speedup vs baseline: 1.0891x; 1.0891x over previous
//
#include <hip/hip_runtime.h>
#include <hip/hip_bf16.h>

typedef __bf16 bf16_t;
typedef __bf16 bf16x4 __attribute__((ext_vector_type(4)));
typedef __bf16 bf16x8 __attribute__((ext_vector_type(8)));
typedef float  f32x4  __attribute__((ext_vector_type(4)));

#define GLD_LDS16(gptr, lptr)                                                        \
    __builtin_amdgcn_global_load_lds((__attribute__((address_space(1))) void*)(gptr),\
                                     (__attribute__((address_space(3))) void*)(lptr),\
                                     16, 0, 0)

constexpr int Bc = 2, Tc = 2048, Ec = 2048, Hc = 16, Dc = 128;
constexpr int Mtok = Bc * Tc;  // 4096

__device__ __forceinline__ bf16x8 cvt8(const float* p) {
    f32x4 a = *(const f32x4*)p;
    f32x4 b = *(const f32x4*)(p + 4);
    bf16x8 r;
    r[0] = (bf16_t)a[0]; r[1] = (bf16_t)a[1];
    r[2] = (bf16_t)a[2]; r[3] = (bf16_t)a[3];
    r[4] = (bf16_t)b[0]; r[5] = (bf16_t)b[1];
    r[6] = (bf16_t)b[2]; r[7] = (bf16_t)b[3];
    return r;
}

// 16-lane butterfly max via DPP (VALU pipe).
__device__ __forceinline__ float fmax_dpp16(float x) {
    int xi;
    xi = __builtin_amdgcn_mov_dpp(__builtin_bit_cast(int, x), 0xB1, 0xF, 0xF, true);
    x = fmaxf(x, __builtin_bit_cast(float, xi));
    xi = __builtin_amdgcn_mov_dpp(__builtin_bit_cast(int, x), 0x4E, 0xF, 0xF, true);
    x = fmaxf(x, __builtin_bit_cast(float, xi));
    xi = __builtin_amdgcn_mov_dpp(__builtin_bit_cast(int, x), 0x141, 0xF, 0xF, true);
    x = fmaxf(x, __builtin_bit_cast(float, xi));
    xi = __builtin_amdgcn_mov_dpp(__builtin_bit_cast(int, x), 0x140, 0xF, 0xF, true);
    x = fmaxf(x, __builtin_bit_cast(float, xi));
    return x;
}

__global__ void convert_bf16(const float* __restrict__ src, bf16_t* __restrict__ dst) {
    size_t i = ((size_t)blockIdx.x * 256 + threadIdx.x) * 8;
    *(bf16x8*)&dst[i] = cvt8(src + i);
}

// Convert Wq,Wk,Wv,Wo (fp32 [E][E]) to one contiguous bf16 buffer w4[4][E][E].
__global__ void convert_w(const float* __restrict__ Wq, const float* __restrict__ Wk,
                          const float* __restrict__ Wv, const float* __restrict__ Wo,
                          bf16_t* __restrict__ w4) {
    int blk = blockIdx.x;          // 0..8191, 2048 blocks per matrix
    int wi  = blk >> 11;           // 0..3
    const float* src = (wi == 0) ? Wq : (wi == 1) ? Wk : (wi == 2) ? Wv : Wo;
    bf16_t* dst = w4 + (size_t)wi * Ec * Ec;
    size_t i = ((size_t)(blk & 2047) * 256 + threadIdx.x) * 8;
    *(bf16x8*)&dst[i] = cvt8(src + i);
}

// ===========================================================================
// Zero-tail fused QKV GEMM (verified: ~102 us, 43% MfmaUtil).
// ===========================================================================
__global__ __launch_bounds__(512, 2) void gemm_qkv_z(const bf16_t* __restrict__ A,
                                                     const bf16_t* __restrict__ w3,
                                                     const float* __restrict__ bq,
                                                     const float* __restrict__ bk,
                                                     const float* __restrict__ bv,
                                                     bf16_t* __restrict__ qo,
                                                     bf16_t* __restrict__ ko,
                                                     bf16_t* __restrict__ vto) {
    __shared__ __align__(16) bf16_t ldsA[3 * 8192];    // [buf][256][32]  48KB
    __shared__ __align__(16) bf16_t ldsB[3 * 12288];   // [buf][384][32]  72KB

    const int tid  = threadIdx.x;
    const int wave = tid >> 6;
    const int lane = tid & 63;
    const int g    = lane >> 4;
    const int n16  = lane & 15;
    const int wm   = wave >> 2;          // 0..1  (M half: 128 rows)
    const int wn   = wave & 3;           // 0..3  (N quarter: 96 cols)
    const int m0   = blockIdx.x * 256;
    const int n0   = blockIdx.y * 384;   // global col in fused N=6144
    const int K    = Ec;

    const int sr   = tid >> 2;                                  // 0..127
    const int scol = (((tid & 3) ^ ((tid >> 3) & 3)) << 3);     // elems
    const bf16_t* srcA = A  + (size_t)(m0 + sr) * K + scol;
    const bf16_t* srcB = w3 + (size_t)(n0 + sr) * K + scol;
    const int dwave = wave * 512;   // wave-uniform dest base (elems)

    const int fsw = (n16 >> 1) & 3;      // read-side swizzle

    constexpr int NT = Ec / 32;  // 64 K-tiles

#define STG_A2(jj, buf)                                                         \
    do { if ((jj) < NT) {                                                       \
        const bf16_t* _s = srcA + (jj) * 32;                                    \
        bf16_t* _d = &ldsA[(buf) * 8192 + dwave];                               \
        GLD_LDS16(_s, _d);                                                      \
        GLD_LDS16(_s + (size_t)128 * K, _d + 4096);                             \
    } } while (0)
#define STG_B1(jj, buf)                                                         \
    do { if ((jj) < NT) {                                                       \
        GLD_LDS16(srcB + (jj) * 32, &ldsB[(buf) * 12288 + dwave]);              \
    } } while (0)
#define STG_B2(jj, buf)                                                         \
    do { if ((jj) < NT) {                                                       \
        const bf16_t* _s = srcB + (jj) * 32;                                    \
        bf16_t* _d = &ldsB[(buf) * 12288 + dwave];                              \
        GLD_LDS16(_s + (size_t)128 * K, _d + 4096);                             \
        GLD_LDS16(_s + (size_t)256 * K, _d + 8192);                             \
    } } while (0)

    f32x4 acc[8][6] = {};
    bf16x8 af[4], af2[4], bfr[6];

    STG_A2(0, 0); STG_B1(0, 0); STG_B2(0, 0);
    STG_A2(1, 1); STG_B1(1, 1); STG_B2(1, 1);
    asm volatile("s_waitcnt vmcnt(5)" ::: "memory");   // tile 0 resident
    __builtin_amdgcn_s_barrier();
    asm volatile("" ::: "memory");

    int bc = 0;  // current buffer
    int bi = 2;  // issue buffer (tile j+2)
#pragma unroll 1
    for (int j = 0; j < NT; ++j) {
        const bf16_t* la = &ldsA[bc * 8192];
        const bf16_t* lb = &ldsB[bc * 12288];

#pragma unroll
        for (int mt = 0; mt < 4; ++mt)
            af[mt] = *(const bf16x8*)&la[(wm * 128 + mt * 16 + n16) * 32 +
                                         ((g ^ fsw) << 3)];
#pragma unroll
        for (int l = 0; l < 6; ++l)
            bfr[l] = *(const bf16x8*)&lb[(wn * 96 + l * 16 + n16) * 32 +
                                         ((g ^ fsw) << 3)];
        STG_A2(j + 2, bi);
        STG_B1(j + 2, bi);
        asm volatile("s_waitcnt lgkmcnt(0)" ::: "memory");
        __builtin_amdgcn_sched_barrier(0);
        __builtin_amdgcn_s_setprio(1);
#pragma unroll
        for (int mt = 0; mt < 4; ++mt)
#pragma unroll
            for (int l = 0; l < 6; ++l)
                acc[mt][l] = __builtin_amdgcn_mfma_f32_16x16x32_bf16(
                    af[mt], bfr[l], acc[mt][l], 0, 0, 0);
        __builtin_amdgcn_s_setprio(0);
        __builtin_amdgcn_s_barrier();
        asm volatile("" ::: "memory");

#pragma unroll
        for (int mt = 0; mt < 4; ++mt)
            af2[mt] = *(const bf16x8*)&la[(wm * 128 + 64 + mt * 16 + n16) * 32 +
                                          ((g ^ fsw) << 3)];
        STG_B2(j + 2, bi);
        asm volatile("s_waitcnt lgkmcnt(0)" ::: "memory");
        __builtin_amdgcn_sched_barrier(0);
        __builtin_amdgcn_s_setprio(1);
#pragma unroll
        for (int mt = 0; mt < 4; ++mt)
#pragma unroll
            for (int l = 0; l < 6; ++l)
                acc[4 + mt][l] = __builtin_amdgcn_mfma_f32_16x16x32_bf16(
                    af2[mt], bfr[l], acc[4 + mt][l], 0, 0, 0);
        __builtin_amdgcn_s_setprio(0);

        if (j < NT - 2)      { asm volatile("s_waitcnt vmcnt(5)" ::: "memory"); }
        else if (j < NT - 1) { asm volatile("s_waitcnt vmcnt(0)" ::: "memory"); }
        __builtin_amdgcn_s_barrier();
        asm volatile("" ::: "memory");

        bc = (bc == 2) ? 0 : bc + 1;
        bi = (bi == 2) ? 0 : bi + 1;
    }
#undef STG_A2
#undef STG_B1
#undef STG_B2

#pragma unroll
    for (int l = 0; l < 6; ++l) {
        int n   = n0 + wn * 96 + l * 16 + n16;
        int mat = n >> 11;            // 0=Q 1=K 2=V
        int nn  = n & 2047;
        const float* bp = (mat == 0) ? bq : (mat == 1) ? bk : bv;
        float bn = bp[nn];
        int h = nn >> 7, d = nn & (Dc - 1);
#pragma unroll
        for (int i = 0; i < 8; ++i) {
            int mb = m0 + wm * 128 + (i >> 2) * 64 + (i & 3) * 16 + g * 4;
            int b = mb >> 11, t = mb & (Tc - 1);
            if (mat == 2) {
                bf16x4 pk;
#pragma unroll
                for (int r = 0; r < 4; ++r) pk[r] = (bf16_t)(acc[i][l][r] + bn);
                *(bf16x4*)&vto[(((size_t)(b * Hc + h)) * Dc + d) * Tc + t] = pk;
            } else {
                bf16_t* outb = (mat == 0) ? qo : ko;
#pragma unroll
                for (int r = 0; r < 4; ++r)
                    outb[(((size_t)(b * Hc + h)) * Tc + (t + r)) * Dc + d] =
                        (bf16_t)(acc[i][l][r] + bn);
            }
        }
    }
}

// ===========================================================================
// Pipelined output-projection GEMM (verified R1).
// ===========================================================================
__global__ __launch_bounds__(512, 2) void gemm_out_p(const bf16_t* __restrict__ A,
                                                     const bf16_t* __restrict__ W,
                                                     const float* __restrict__ bias,
                                                     float* __restrict__ out) {
    __shared__ __align__(16) bf16_t ldsA[3 * 256 * 32];
    __shared__ __align__(16) bf16_t ldsB[3 * 128 * 32];

    const int tid  = threadIdx.x;
    const int wave = tid >> 6;
    const int lane = tid & 63;
    const int g    = lane >> 4;
    const int n16  = lane & 15;
    const int wm   = wave >> 1;
    const int wn   = wave & 1;
    const int m0   = blockIdx.x * 256;
    const int n0   = blockIdx.y * 128;
    const int K    = Ec;

    const int sr   = tid >> 2;
    const int scol = (((tid & 3) ^ ((tid >> 3) & 3)) << 3);
    const bf16_t* gA0 = A + (size_t)(m0 + sr) * K + scol;
    const bf16_t* gA1 = A + (size_t)(m0 + 128 + sr) * K + scol;
    const bf16_t* gB  = W + (size_t)(n0 + sr) * K + scol;
    const int dL = wave * 512;

    const int fsw = (n16 >> 1) & 3;
    const int rAo = (wm * 64 + n16) * 32 + ((g ^ fsw) << 3);
    const int rBo = (wn * 64 + n16) * 32 + ((g ^ fsw) << 3);

    f32x4 acc[4][4] = {};

    constexpr int NT = Ec / 32;
#pragma unroll
    for (int tt = 0; tt < 2; ++tt) {
        GLD_LDS16(gA0 + tt * 32, &ldsA[tt * 8192 + dL]);
        GLD_LDS16(gA1 + tt * 32, &ldsA[tt * 8192 + 4096 + dL]);
        GLD_LDS16(gB  + tt * 32, &ldsB[tt * 4096 + dL]);
    }

    int bc = 0, bi = 2;
#pragma unroll 1
    for (int t = 0; t < NT; ++t) {
        if (t < NT - 1) { asm volatile("s_waitcnt vmcnt(3)" ::: "memory"); }
        else            { asm volatile("s_waitcnt vmcnt(0)" ::: "memory"); }
        __builtin_amdgcn_s_barrier();
        asm volatile("" ::: "memory");

        const bf16_t* la = &ldsA[bc * 8192];
        const bf16_t* lb = &ldsB[bc * 4096];
        bf16x8 af[4], bfr[4];
#pragma unroll
        for (int mt = 0; mt < 4; ++mt) af[mt] = *(const bf16x8*)&la[rAo + mt * 512];
#pragma unroll
        for (int nt = 0; nt < 4; ++nt) bfr[nt] = *(const bf16x8*)&lb[rBo + nt * 512];

        if (t + 2 < NT) {
            GLD_LDS16(gA0 + (t + 2) * 32, &ldsA[bi * 8192 + dL]);
            GLD_LDS16(gA1 + (t + 2) * 32, &ldsA[bi * 8192 + 4096 + dL]);
            GLD_LDS16(gB  + (t + 2) * 32, &ldsB[bi * 4096 + dL]);
        }

        asm volatile("s_waitcnt lgkmcnt(0)" ::: "memory");
        __builtin_amdgcn_sched_barrier(0);
        __builtin_amdgcn_s_setprio(1);
#pragma unroll
        for (int mt = 0; mt < 4; ++mt)
#pragma unroll
            for (int nt = 0; nt < 4; ++nt)
                acc[mt][nt] = __builtin_amdgcn_mfma_f32_16x16x32_bf16(
                    af[mt], bfr[nt], acc[mt][nt], 0, 0, 0);
        __builtin_amdgcn_s_setprio(0);

        bc = (bc == 2) ? 0 : bc + 1;
        bi = (bi == 2) ? 0 : bi + 1;
    }

    const int row_off = wm * 64;
    const int col_off = wn * 64;
#pragma unroll
    for (int nt = 0; nt < 4; ++nt) {
        int n = n0 + col_off + nt * 16 + n16;
        float bn = bias[n];
#pragma unroll
        for (int mt = 0; mt < 4; ++mt) {
            int mb = m0 + row_off + mt * 16 + g * 4;
#pragma unroll
            for (int r = 0; r < 4; ++r)
                out[(size_t)(mb + r) * Ec + n] = acc[mt][nt][r] + bn;
        }
    }
}

// ---------------------------------------------------------------------------
// Fallback variants (fp32 weights, register-staged) — small-workspace path.
// ---------------------------------------------------------------------------
__global__ __launch_bounds__(256) void gemm_qkv(const bf16_t* __restrict__ A,
                                                const float* __restrict__ Wq,
                                                const float* __restrict__ Wk,
                                                const float* __restrict__ Wv,
                                                const float* __restrict__ bq,
                                                const float* __restrict__ bk,
                                                const float* __restrict__ bv,
                                                bf16_t* __restrict__ qo,
                                                bf16_t* __restrict__ ko,
                                                bf16_t* __restrict__ vto) {
    __shared__ __align__(16) bf16_t ldsA[128 * 32];
    __shared__ __align__(16) bf16_t ldsB[128 * 32];

    const int tid  = threadIdx.x;
    const int wave = tid >> 6;
    const int lane = tid & 63;
    const int g    = lane >> 4;
    const int n16  = lane & 15;
    const int m0   = blockIdx.x * 128;
    const int mat  = blockIdx.y >> 4;
    const int n0   = (blockIdx.y & 15) * 128;
    const int row_off = (wave >> 1) * 64;
    const int col_off = (wave & 1) * 64;
    const int K = Ec;

    const float* W    = (mat == 0) ? Wq : (mat == 1) ? Wk : Wv;
    const float* bias = (mat == 0) ? bq : (mat == 1) ? bk : bv;

    f32x4 acc[4][4] = {};

    const int r0 = tid >> 2;
    const int cc = tid & 3;
    const size_t a0 = (size_t)(m0 + r0) * K + cc * 8;
    const size_t a1 = (size_t)(m0 + r0 + 64) * K + cc * 8;
    const float* pb0 = W + (size_t)(n0 + r0) * K + cc * 8;
    const float* pb1 = W + (size_t)(n0 + r0 + 64) * K + cc * 8;

    for (int k0 = 0; k0 < K; k0 += 32) {
        bf16x8 vb0 = cvt8(pb0 + k0);
        bf16x8 vb1 = cvt8(pb1 + k0);
        __syncthreads();
        GLD_LDS16(A + a0 + k0, &ldsA[(wave * 64) * 8]);
        GLD_LDS16(A + a1 + k0, &ldsA[(256 + wave * 64) * 8]);
        *(bf16x8*)&ldsB[(size_t)tid * 8]         = vb0;
        *(bf16x8*)&ldsB[(size_t)(256 + tid) * 8] = vb1;
        __syncthreads();

        bf16x8 af[4], bfr[4];
#pragma unroll
        for (int mt = 0; mt < 4; ++mt)
            af[mt] = *(const bf16x8*)&ldsA[(row_off + mt * 16 + n16) * 32 + g * 8];
#pragma unroll
        for (int nt = 0; nt < 4; ++nt)
            bfr[nt] = *(const bf16x8*)&ldsB[(col_off + nt * 16 + n16) * 32 + g * 8];
#pragma unroll
        for (int mt = 0; mt < 4; ++mt)
#pragma unroll
            for (int nt = 0; nt < 4; ++nt)
                acc[mt][nt] = __builtin_amdgcn_mfma_f32_16x16x32_bf16(
                    af[mt], bfr[nt], acc[mt][nt], 0, 0, 0);
    }

#pragma unroll
    for (int nt = 0; nt < 4; ++nt) {
        int n = n0 + col_off + nt * 16 + n16;
        float bn = bias[n];
        int h = n >> 7, d = n & (Dc - 1);
#pragma unroll
        for (int mt = 0; mt < 4; ++mt) {
            int mb = m0 + row_off + mt * 16 + g * 4;
            int b = mb >> 11, t = mb & (Tc - 1);
            if (mat == 2) {
                bf16x4 pk;
#pragma unroll
                for (int r = 0; r < 4; ++r) pk[r] = (bf16_t)(acc[mt][nt][r] + bn);
                *(bf16x4*)&vto[(((size_t)(b * Hc + h)) * Dc + d) * Tc + t] = pk;
            } else {
                bf16_t* outb = (mat == 0) ? qo : ko;
#pragma unroll
                for (int r = 0; r < 4; ++r)
                    outb[(((size_t)(b * Hc + h)) * Tc + (t + r)) * Dc + d] =
                        (bf16_t)(acc[mt][nt][r] + bn);
            }
        }
    }
}

__global__ __launch_bounds__(256) void gemm_out(const bf16_t* __restrict__ A,
                                                const float* __restrict__ W,
                                                const float* __restrict__ bias,
                                                float* __restrict__ out,
                                                int M, int N, int K) {
    __shared__ __align__(16) bf16_t ldsA[128 * 32];
    __shared__ __align__(16) bf16_t ldsB[128 * 32];

    const int tid  = threadIdx.x;
    const int wave = tid >> 6;
    const int lane = tid & 63;
    const int g    = lane >> 4;
    const int n16  = lane & 15;
    const int m0 = blockIdx.x * 128;
    const int n0 = blockIdx.y * 128;
    const int row_off = (wave >> 1) * 64;
    const int col_off = (wave & 1) * 64;

    f32x4 acc[4][4] = {};

    const int r0 = tid >> 2;
    const int cc = tid & 3;
    const size_t a0 = (size_t)(m0 + r0) * K + cc * 8;
    const size_t a1 = (size_t)(m0 + r0 + 64) * K + cc * 8;
    const float* pb0 = W + (size_t)(n0 + r0) * K + cc * 8;
    const float* pb1 = W + (size_t)(n0 + r0 + 64) * K + cc * 8;

    for (int k0 = 0; k0 < K; k0 += 32) {
        bf16x8 vb0 = cvt8(pb0 + k0);
        bf16x8 vb1 = cvt8(pb1 + k0);
        __syncthreads();
        GLD_LDS16(A + a0 + k0, &ldsA[(wave * 64) * 8]);
        GLD_LDS16(A + a1 + k0, &ldsA[(256 + wave * 64) * 8]);
        *(bf16x8*)&ldsB[(size_t)tid * 8]         = vb0;
        *(bf16x8*)&ldsB[(size_t)(256 + tid) * 8] = vb1;
        __syncthreads();

        bf16x8 af[4], bfr[4];
#pragma unroll
        for (int mt = 0; mt < 4; ++mt)
            af[mt] = *(const bf16x8*)&ldsA[(row_off + mt * 16 + n16) * 32 + g * 8];
#pragma unroll
        for (int nt = 0; nt < 4; ++nt)
            bfr[nt] = *(const bf16x8*)&ldsB[(col_off + nt * 16 + n16) * 32 + g * 8];
#pragma unroll
        for (int mt = 0; mt < 4; ++mt)
#pragma unroll
            for (int nt = 0; nt < 4; ++nt)
                acc[mt][nt] = __builtin_amdgcn_mfma_f32_16x16x32_bf16(
                    af[mt], bfr[nt], acc[mt][nt], 0, 0, 0);
    }

#pragma unroll
    for (int nt = 0; nt < 4; ++nt) {
        int n = n0 + col_off + nt * 16 + n16;
        float bn = bias[n];
#pragma unroll
        for (int mt = 0; mt < 4; ++mt) {
            int mb = m0 + row_off + mt * 16 + g * 4;
#pragma unroll
            for (int r = 0; r < 4; ++r)
                out[(size_t)(mb + r) * N + n] = acc[mt][nt][r] + bn;
        }
    }
}

// ---------------------------------------------------------------------------
// RoPE in-place on q,k [B,H,T,D]; positions 1-indexed (t+1).
// ---------------------------------------------------------------------------
__global__ void rope_kernel(bf16_t* __restrict__ q, bf16_t* __restrict__ k) {
    int row = blockIdx.x * 4 + (threadIdx.x >> 6);  // (b*H+h)*T + t
    int d   = threadIdx.x & 63;
    int t   = row & (Tc - 1);
    float theta = powf(10000.0f, -(float)d * (1.0f / 64.0f));
    float ang   = (float)(t + 1) * theta;
    float sv, cv;
    sincosf(ang, &sv, &cv);
    size_t base = (size_t)row * Dc;
    float q1 = (float)q[base + d], q2 = (float)q[base + d + 64];
    q[base + d]      = (bf16_t)(q1 * cv - q2 * sv);
    q[base + d + 64] = (bf16_t)(q2 * cv + q1 * sv);
    float k1 = (float)k[base + d], k2 = (float)k[base + d + 64];
    k[base + d]      = (bf16_t)(k1 * cv - k2 * sv);
    k[base + d + 64] = (bf16_t)(k2 * cv + k1 * sv);
}

// ---------------------------------------------------------------------------
// Causal flash attention — R7-proven configuration (padded LDS, 2D grid,
// in-kernel sc2, classic online softmax, DPP max) + exact-skip rescale:
// when no row's running max changed this tile, alpha==1.0 exactly
// (exp2(0)=1), so the 32-multiply o_acc rescale pass is an identity and
// is skipped under a wave-uniform __any guard. Numerically identical.
// Block = 4 waves = 64 queries per q-tile; block pi handles q-tiles
// {31-pi, pi}: uniform 33 K-tiles per block.
// ---------------------------------------------------------------------------
constexpr int KP = 128 + 8;  // k_lds row pitch
constexpr int VP = 64 + 8;   // v_lds row pitch
constexpr int PP = 64 + 8;   // p_lds row pitch

__global__ __launch_bounds__(256) void attn_kernel(const bf16_t* __restrict__ q,
                                                   const bf16_t* __restrict__ kmat,
                                                   const bf16_t* __restrict__ vt,
                                                   bf16_t* __restrict__ out) {
    __shared__ __align__(16) bf16_t k_lds[64 * KP];
    __shared__ __align__(16) bf16_t v_lds[128 * VP];
    __shared__ __align__(16) bf16_t p_lds[4 * 16 * PP];

    const int tid  = threadIdx.x;
    const int wave = tid >> 6, lane = tid & 63;
    const int g = lane >> 4, n16 = lane & 15;
    const int pi = blockIdx.x;   // 0..15
    const int bh = blockIdx.y;
    const size_t base = (size_t)bh * Tc * Dc;
    const int b = bh >> 4, h = bh & 15;
    const float sc2 = 0.08838834764831845f * 1.4426950408889634f;  // /sqrt(D)*log2e
    bf16_t* pw = &p_lds[wave * 16 * PP];

    const int kr_key = tid >> 4, kr_c = tid & 15;   // K staging: row i*16+kr_key
    const int vr_dd  = tid >> 3, vr_c = tid & 7;    // V staging: row i*32+vr_dd

#pragma unroll 1
    for (int half = 0; half < 2; ++half) {
        const int qt = half ? pi : 31 - pi;
        const int q0 = qt * 64;

        bf16x8 qf[4];
        {
            const bf16_t* qp = q + base + (size_t)(q0 + wave * 16 + n16) * Dc + g * 8;
#pragma unroll
            for (int kk = 0; kk < 4; ++kk) qf[kk] = *(const bf16x8*)(qp + kk * 32);
        }

        float m_run[4], l_run[4];
#pragma unroll
        for (int r = 0; r < 4; ++r) { m_run[r] = -1e30f; l_run[r] = 0.0f; }
        f32x4 o_acc[8] = {};

        // preload tile 0 into registers
        bf16x8 rk[4], rv[4];
#pragma unroll
        for (int i = 0; i < 4; ++i)
            rk[i] = *(const bf16x8*)&kmat[base + (size_t)(i * 16 + kr_key) * Dc + kr_c * 8];
#pragma unroll
        for (int i = 0; i < 4; ++i)
            rv[i] = *(const bf16x8*)&vt[base + (size_t)(i * 32 + vr_dd) * Tc + vr_c * 8];

#pragma unroll 1
        for (int kt = 0; kt <= qt; ++kt) {
            const int k0 = kt * 64;
            __syncthreads();  // prior tile's LDS readers done
#pragma unroll
            for (int i = 0; i < 4; ++i)
                *(bf16x8*)&k_lds[(i * 16 + kr_key) * KP + kr_c * 8] = rk[i];
#pragma unroll
            for (int i = 0; i < 4; ++i)
                *(bf16x8*)&v_lds[(i * 32 + vr_dd) * VP + vr_c * 8] = rv[i];
            __syncthreads();  // staging visible

            if (kt < qt) {  // prefetch next tile (consumed at next ds_write)
                const int kn = k0 + 64;
#pragma unroll
                for (int i = 0; i < 4; ++i)
                    rk[i] = *(const bf16x8*)&kmat[base + (size_t)(kn + i * 16 + kr_key) * Dc + kr_c * 8];
#pragma unroll
                for (int i = 0; i < 4; ++i)
                    rv[i] = *(const bf16x8*)&vt[base + (size_t)(i * 32 + vr_dd) * Tc + kn + vr_c * 8];
            }

            // S = Q K^T (16 q x 64 keys per wave)
            f32x4 s_acc[4];
#pragma unroll
            for (int nt = 0; nt < 4; ++nt) {
                f32x4 a = {};
                int key = nt * 16 + n16;
#pragma unroll
                for (int kk = 0; kk < 4; ++kk) {
                    bf16x8 kf = *(const bf16x8*)&k_lds[key * KP + kk * 32 + g * 8];
                    a = __builtin_amdgcn_mfma_f32_16x16x32_bf16(qf[kk], kf, a, 0, 0, 0);
                }
                s_acc[nt] = a;
            }

            if (kt == qt) {  // diagonal: causal mask
#pragma unroll
                for (int nt = 0; nt < 4; ++nt) {
                    int key = k0 + nt * 16 + n16;
#pragma unroll
                    for (int r = 0; r < 4; ++r) {
                        int qq = q0 + wave * 16 + g * 4 + r;
                        float v = s_acc[nt][r] * sc2;
                        s_acc[nt][r] = (key <= qq) ? v : -1e30f;
                    }
                }
            } else {
#pragma unroll
                for (int nt = 0; nt < 4; ++nt)
#pragma unroll
                    for (int r = 0; r < 4; ++r) s_acc[nt][r] *= sc2;
            }

            // online softmax (exp2 domain); DPP butterfly for the 16-lane max
            float alpha[4];
            int chg = 0;
#pragma unroll
            for (int r = 0; r < 4; ++r) {
                float rm = fmaxf(fmaxf(s_acc[0][r], s_acc[1][r]),
                                 fmaxf(s_acc[2][r], s_acc[3][r]));
                rm = fmax_dpp16(rm);
                float m_new = fmaxf(m_run[r], rm);
                alpha[r] = __builtin_amdgcn_exp2f(m_run[r] - m_new);
                chg |= (m_new > m_run[r]);
                m_run[r] = m_new;
                float sum = 0.0f;
#pragma unroll
                for (int nt = 0; nt < 4; ++nt) {
                    float p = __builtin_amdgcn_exp2f(s_acc[nt][r] - m_new);
                    s_acc[nt][r] = p;
                    sum += p;
                }
                l_run[r] = l_run[r] * alpha[r] + sum;  // per-lane partial
            }
            if (__any(chg)) {   // alpha==1.0 exactly when max unchanged
#pragma unroll
                for (int dt = 0; dt < 8; ++dt)
#pragma unroll
                    for (int r = 0; r < 4; ++r) o_acc[dt][r] *= alpha[r];
            }

            // P (C/D) -> wave-private LDS [q][key]  (no barrier needed)
#pragma unroll
            for (int nt = 0; nt < 4; ++nt) {
                int key = nt * 16 + n16;
#pragma unroll
                for (int r = 0; r < 4; ++r)
                    pw[(g * 4 + r) * PP + key] = (bf16_t)s_acc[nt][r];
            }
            bf16x8 pf[2];
#pragma unroll
            for (int kk = 0; kk < 2; ++kk)
                pf[kk] = *(const bf16x8*)&pw[n16 * PP + kk * 32 + g * 8];

            // O += P V
#pragma unroll
            for (int dt = 0; dt < 8; ++dt) {
                int dd = dt * 16 + n16;
#pragma unroll
                for (int kk = 0; kk < 2; ++kk) {
                    bf16x8 vf = *(const bf16x8*)&v_lds[dd * VP + kk * 32 + g * 8];
                    o_acc[dt] = __builtin_amdgcn_mfma_f32_16x16x32_bf16(
                        pf[kk], vf, o_acc[dt], 0, 0, 0);
                }
            }
        }

        // epilogue: reduce per-lane l partials across the 16-lane row, write out
        float inv_l[4];
#pragma unroll
        for (int r = 0; r < 4; ++r) {
            float s = l_run[r];
            s += __shfl_xor(s, 1, 16);
            s += __shfl_xor(s, 2, 16);
            s += __shfl_xor(s, 4, 16);
            s += __shfl_xor(s, 8, 16);
            inv_l[r] = 1.0f / s;
        }
#pragma unroll
        for (int dt = 0; dt < 8; ++dt) {
            int d = dt * 16 + n16;
#pragma unroll
            for (int r = 0; r < 4; ++r) {
                int qq = q0 + wave * 16 + g * 4 + r;
                out[((size_t)(b * Tc + qq)) * Ec + h * Dc + d] =
                    (bf16_t)(o_acc[dt][r] * inv_l[r]);
            }
        }
    }
}

// ---------------------------------------------------------------------------
extern "C" void kernel_launch(void* const* d_in, const int* in_sizes, int n_in,
                              void* d_out, int out_size, void* d_ws, size_t ws_size,
                              hipStream_t stream) {
    const float* x  = (const float*)d_in[0];
    const float* Wq = (const float*)d_in[1];
    const float* bq = (const float*)d_in[2];
    const float* Wk = (const float*)d_in[3];
    const float* bk = (const float*)d_in[4];
    const float* Wv = (const float*)d_in[5];
    const float* bv = (const float*)d_in[6];
    const float* Wo = (const float*)d_in[7];
    const float* bo = (const float*)d_in[8];
    float* out = (float*)d_out;

    char* ws = (char*)d_ws;
    const size_t sz  = (size_t)Bc * Hc * Tc * Dc * sizeof(bf16_t);  // 16.78 MB
    const size_t szW = (size_t)Ec * Ec * sizeof(bf16_t);            // 8.39 MB
    bf16_t* q   = (bf16_t*)(ws);            // R0
    bf16_t* k   = (bf16_t*)(ws + sz);       // R1
    bf16_t* vt  = (bf16_t*)(ws + 2 * sz);   // R2 (written transposed)
    bf16_t* xb  = (bf16_t*)(ws + 3 * sz);   // R3: xb, then att
    bf16_t* att = xb;

    if (ws_size >= 4 * sz + 4 * szW) {
        // bf16 weights + zero-tail fused QKV GEMM + pipelined out GEMM
        bf16_t* w4 = (bf16_t*)(ws + 4 * sz);       // [4][E][E]: Wq,Wk,Wv,Wo
        convert_bf16<<<Mtok * Ec / (256 * 8), 256, 0, stream>>>(x, xb);
        convert_w<<<8192, 256, 0, stream>>>(Wq, Wk, Wv, Wo, w4);
        gemm_qkv_z<<<dim3(Mtok / 256, 16), 512, 0, stream>>>(xb, w4, bq, bk, bv,
                                                             q, k, vt);
        rope_kernel<<<Bc * Hc * Tc / 4, 256, 0, stream>>>(q, k);
        attn_kernel<<<dim3(16, Bc * Hc), 256, 0, stream>>>(q, k, vt, att);
        gemm_out_p<<<dim3(Mtok / 256, Ec / 128), 512, 0, stream>>>(
            att, w4 + 3 * (size_t)Ec * Ec, bo, out);
    } else {
        // fallback: fp32 weights, register-staged (proven path)
        convert_bf16<<<Mtok * Ec / (256 * 8), 256, 0, stream>>>(x, xb);
        gemm_qkv<<<dim3(Mtok / 128, 48), 256, 0, stream>>>(xb, Wq, Wk, Wv,
                                                           bq, bk, bv, q, k, vt);
        rope_kernel<<<Bc * Hc * Tc / 4, 256, 0, stream>>>(q, k);
        attn_kernel<<<dim3(16, Bc * Hc), 256, 0, stream>>>(q, k, vt, att);
        gemm_out<<<dim3(Mtok / 128, Ec / 128), 256, 0, stream>>>(att, Wo, bo, out,
                                                                 Mtok, Ec, Ec);
    }
}